// Round 1
// 254.033 us; speedup vs baseline: 1.0370x; 1.0370x over previous
//
#include <hip/hip_runtime.h>

#define NUM_NET 2
#define V 100000
#define D 128
#define B 4096
#define K 5
#define NS 10

// weight magnitude classes (sign is folded into the logsigmoid argument)
#define W_A (1.0f/20480.0f)   // 1/(B*K)      main pos
#define W_B (1.0f/4096.0f)    // 1/B          neg_main
#define W_C (0.1f/4096.0f)    // HYP/B        node/cross-neg/role
#define W_D (0.1f/20480.0f)   // HYP2/(B*K)   cross pos

#define NBINS 64
#define PIPE 4

// DPP-based add: v + dpp_perm(v). CTRL: 0xB1=quad_perm(1,0,3,2) (xor1),
// 0x4E=quad_perm(2,3,0,1) (xor2), 0x124=row_ror:4, 0x128=row_ror:8.
template <int CTRL>
__device__ __forceinline__ float dpp_xadd(float v) {
    int r = __builtin_amdgcn_update_dpp(0, __float_as_int(v), CTRL, 0xF, 0xF, true);
    return v + __int_as_float(r);
}

__device__ __forceinline__ float lsig(float x) {
    return fminf(x, 0.0f) - __logf(1.0f + __expf(-fabsf(x)));
}

__global__ __launch_bounds__(256) void rmne_main(
    const float* __restrict__ node_tables,
    const float* __restrict__ neigh_tables,
    const int*   __restrict__ nodes_idx,
    const int*   __restrict__ neigh_idx,
    const int*   __restrict__ role_idx,
    const int*   __restrict__ neg_main,
    const int*   __restrict__ neg_node,
    const int*   __restrict__ neg_cross,
    const int*   __restrict__ neg_role,
    float*       __restrict__ ws)
{
    const int tid  = threadIdx.x;
    const int lane = tid & 63;
    const int wave = tid >> 6;
    const int unit = blockIdx.x * 4 + wave;   // 8192 units total
    const int i = unit >> 12;                 // net index (0/1)
    const int b = unit & (B - 1);
    const int j = 1 - i;

    // ---- 144-entry (idx|tab) list in 3 per-lane register slots ----
    // d = lane + 64*s; d==143 is a zero-weight pad (skipped at consume).
    int pk[3];
    #pragma unroll
    for (int s = 0; s < 3; ++s) {
        int d = lane + 64 * s;
        int idx = 0; int tab = 0;  // tab: 0/1 node net, 2/3 neigh net
        if      (d <   5) { idx = neigh_idx[(i*B + b)*K + d];             tab = 2 + i; }
        else if (d <  55) { idx = neg_main[(i*B + b)*50 + (d-5)];         tab = 2 + i; }
        else if (d <  56) { idx = nodes_idx[i*B + b];                     tab = j;     }
        else if (d <  66) { idx = neg_node[((i*2+j)*B + b)*NS + (d-56)];  tab = j;     }
        else if (d <  71) { idx = neigh_idx[(i*B + b)*K + (d-66)];        tab = 2 + j; }
        else if (d < 121) { idx = neg_cross[((i*2+j)*B + b)*50 + (d-71)]; tab = 2 + j; }
        else if (d < 122) { idx = role_idx[(i*2+0)*B + b];                tab = 0;     }
        else if (d < 132) { idx = neg_role[((i*2+0)*B + b)*NS + (d-122)]; tab = 0;     }
        else if (d < 133) { idx = role_idx[(i*2+1)*B + b];                tab = 1;     }
        else if (d < 143) { idx = neg_role[((i*2+1)*B + b)*NS + (d-133)]; tab = 1;     }
        pk[s] = idx | (tab << 20);
    }

    // ---- node embedding fragment: quarter-wave layout, 8 dims/lane ----
    const int l16     = lane & 15;
    const int quarter = lane >> 4;
    const int nrow    = nodes_idx[i*B + b];
    const float4* nep = (const float4*)(node_tables + ((size_t)i*V + (size_t)nrow)*D) + l16*2;
    const float4 ne0 = nep[0];
    const float4 ne1 = nep[1];

    // ---- 4-deep register prefetch pipeline (all indices static via full unroll) ----
    float4 c0b[PIPE], c1b[PIPE];

    auto issue = [&](int t) {
        int s   = t >> 4;
        int src = (4*t + quarter) & 63;
        int p   = __shfl(pk[s], src, 64);
        int idx = p & 0xFFFFF;
        int tab = p >> 20;
        const float* base = (tab & 2) ? neigh_tables : node_tables;
        const float4* row = (const float4*)(base + ((size_t)(tab & 1)*V + (size_t)idx)*D) + l16*2;
        c0b[t & (PIPE-1)] = row[0];
        c1b[t & (PIPE-1)] = row[1];
    };

    float accA = 0.0f, accB = 0.0f, accC = 0.0f, accG = 0.0f;

    #pragma unroll
    for (int t = 0; t < PIPE; ++t) issue(t);

    // d = 4t + quarter. Section -> (class, sign) is compile-time per t except
    // boundary t in {1,13,16,17,30,33,35} which need a per-quarter select.
    #pragma unroll
    for (int t = 0; t < 36; ++t) {
        if (t + PIPE < 36) issue(t + PIPE);
        float4 c0 = c0b[t & (PIPE-1)];
        float4 c1 = c1b[t & (PIPE-1)];
        float pp = ne0.x*c0.x + ne0.y*c0.y + ne0.z*c0.z + ne0.w*c0.w
                 + ne1.x*c1.x + ne1.y*c1.y + ne1.z*c1.z + ne1.w*c1.w;
        // 16-lane reduce, pure VALU (DPP): quad sums then ror4+ror8 rotation
        pp = dpp_xadd<0xB1>(pp);
        pp = dpp_xadd<0x4E>(pp);
        pp = dpp_xadd<0x124>(pp);
        pp = dpp_xadd<0x128>(pp);

        if (t == 0) {                               // d 0..3: A+
            accA += lsig(pp);
        } else if (t == 1) {                        // d 4: A+ | d 5..7: B-
            float x  = (quarter == 0) ? pp : -pp;
            float mw = (quarter == 0) ? W_A : W_B;
            accG = fmaf(mw, lsig(x), accG);
        } else if (t <= 12) {                       // d 8..51: B-
            accB += lsig(-pp);
        } else if (t == 13) {                       // d 52..54: B- | d 55: C+
            float x  = (quarter == 3) ? pp : -pp;
            float mw = (quarter == 3) ? W_C : W_B;
            accG = fmaf(mw, lsig(x), accG);
        } else if (t <= 15) {                       // d 56..63: C-
            accC += lsig(-pp);
        } else if (t == 16) {                       // d 64,65: C- | d 66,67: D+
            float x  = (quarter >= 2) ? pp : -pp;
            float mw = (quarter >= 2) ? W_D : W_C;
            accG = fmaf(mw, lsig(x), accG);
        } else if (t == 17) {                       // d 68..70: D+ | d 71: C-
            float x  = (quarter == 3) ? -pp : pp;
            float mw = (quarter == 3) ? W_C : W_D;
            accG = fmaf(mw, lsig(x), accG);
        } else if (t <= 29) {                       // d 72..119: C-
            accC += lsig(-pp);
        } else if (t == 30) {                       // d 120: C- | 121: C+ | 122,123: C-
            float x = (quarter == 1) ? pp : -pp;
            accC += lsig(x);
        } else if (t <= 32) {                       // d 124..131: C-
            accC += lsig(-pp);
        } else if (t == 33) {                       // d 132: C+ | 133..135: C-
            float x = (quarter == 0) ? pp : -pp;
            accC += lsig(x);
        } else if (t == 34) {                       // d 136..139: C-
            accC += lsig(-pp);
        } else {                                    // t==35: d 140..142: C- | 143: pad
            float ls = lsig(-pp);
            accC += (quarter == 3) ? 0.0f : ls;
        }
    }

    float acc = W_A*accA + W_B*accB + W_C*accC + accG;

    // combine quarters: values identical within each 16-lane row, so xor16+xor32
    // adds exactly one representative from each quarter -> S_unit on all lanes.
    acc += __shfl_xor(acc, 16, 64);
    acc += __shfl_xor(acc, 32, 64);

    __shared__ float wsum[4];
    if (lane == 0) wsum[wave] = acc;
    __syncthreads();
    if (tid == 0) {
        float s = wsum[0] + wsum[1] + wsum[2] + wsum[3];
        atomicAdd(ws + (blockIdx.x & (NBINS - 1)), s);
    }
}

__global__ void rmne_finalize(const float* __restrict__ ws, float* __restrict__ out)
{
    float v = ws[threadIdx.x];
    v += __shfl_xor(v, 1, 64);
    v += __shfl_xor(v, 2, 64);
    v += __shfl_xor(v, 4, 64);
    v += __shfl_xor(v, 8, 64);
    v += __shfl_xor(v, 16, 64);
    v += __shfl_xor(v, 32, 64);
    if (threadIdx.x == 0) out[0] = v * (-1.0f / 10.0f);
}

extern "C" void kernel_launch(void* const* d_in, const int* in_sizes, int n_in,
                              void* d_out, int out_size, void* d_ws, size_t ws_size,
                              hipStream_t stream) {
    const float* node_tables  = (const float*)d_in[0];
    const float* neigh_tables = (const float*)d_in[1];
    const int*   nodes_idx    = (const int*)d_in[2];
    const int*   neigh_idx    = (const int*)d_in[3];
    const int*   role_idx     = (const int*)d_in[4];
    const int*   neg_main     = (const int*)d_in[5];
    const int*   neg_node     = (const int*)d_in[6];
    const int*   neg_cross    = (const int*)d_in[7];
    const int*   neg_role     = (const int*)d_in[8];
    float* ws  = (float*)d_ws;
    float* out = (float*)d_out;

    hipMemsetAsync(ws, 0, NBINS * sizeof(float), stream);
    rmne_main<<<2048, 256, 0, stream>>>(node_tables, neigh_tables, nodes_idx, neigh_idx,
                                        role_idx, neg_main, neg_node, neg_cross, neg_role, ws);
    rmne_finalize<<<1, 64, 0, stream>>>(ws, out);
}